// Round 21
// baseline (117.294 us; speedup 1.0000x reference)
//
#include <hip/hip_runtime.h>

// RelGraphConv basis-decomposition forward, MI355X.
//
// Input-space reformulation:
//   g[d, b, :] = sum_{e: dst_e = d} w_comp[et_e, b] * feat[src_e, :]   (b = 0,1)
//   out[d]     = [g0 | g1 | feat](192) @ Wcat(192x64) + bias,
//                Wcat = [V0; V1; W_loop]
//
// Pipeline (3 dispatches + memset):
//   memset(bcnt)  : per-bucket counts start at 0
//   k_scatter_prep: 512 thr; blocks 0..195 = coarse 391-bucket multisplit
//                   (SC_CHUNK=8192) into fixed-capacity buckets; then
//                   feat->bf16; Wcat^T->bf16
//   k_fine        : per-bucket exact per-node CSR (LDS hist+scan, 1024 thr)
//   k_gather_post : 16 nodes/block (r19 config). Phase 1 = interleaved A/B
//                   pair with 3-STAGE PIPELINE: entries n+1 AND feats n+1
//                   issued while feats n are in flight (~32 feat reqs in
//                   flight per wave). Phase 2 = 16x64x192 MFMA tile.

constexpr int N_NODES  = 100000;
constexpr int N_EDGES  = 1600000;
constexpr int IN_FEAT  = 64;
constexpr int OUT_FEAT = 64;

constexpr int BN  = 256;                               // nodes per bucket
constexpr int NB  = (N_NODES + BN - 1) / BN;           // 391 buckets
constexpr int CAP = 4608;                              // bucket capacity (+8 sigma)
constexpr int SC_CHUNK = 8192;                         // edges per scatter block
constexpr int NCH = (N_EDGES + SC_CHUNK - 1) / SC_CHUNK;  // 196 scatter blocks
constexpr int CVT_BLOCKS = 512;                        // feat cvt blocks (512 thr)
constexpr int W_BLOCKS = 25;                           // 64*LROW/512 wtb blocks

constexpr int NPG = 16;                                // nodes per gather block
constexpr int N_GRP = N_NODES / NPG;                   // 6250 (exact)
constexpr int LROW = 200;                              // padded row (bf16)

typedef __attribute__((ext_vector_type(8))) short bf16x8;
typedef __attribute__((ext_vector_type(4))) float f32x4;

// entry pack: dst_low(8) | src(17) | etype(6)
__device__ __forceinline__ unsigned pack_entry(int d, int s, int r) {
    return (unsigned)(d & (BN - 1)) | ((unsigned)s << 8) | ((unsigned)r << 25);
}

__device__ __forceinline__ unsigned bf16_rne(float f) {
    unsigned b = __float_as_uint(f);
    b += 0x7fffu + ((b >> 16) & 1u);
    return b >> 16;
}

// ------------------------------------------------- fused scatter + convert
__global__ __launch_bounds__(512) void k_scatter_prep(
    const int* __restrict__ src, const int* __restrict__ dst,
    const int* __restrict__ et,  int* __restrict__ bcnt,
    unsigned* __restrict__ sorted_c,
    const float* __restrict__ feat, unsigned* __restrict__ fbf,
    const float* __restrict__ weight, const float* __restrict__ loop_weight,
    unsigned short* __restrict__ wtb)
{
    __shared__ int hist[NB], gb[NB], lcur[NB];
    const int b = blockIdx.x, t = threadIdx.x;

    if (b < NCH) {  // ---- multisplit scatter chunk ----
        const int cbase = b * SC_CHUNK;
        for (int i = t; i < NB; i += 512) { hist[i] = 0; lcur[i] = 0; }
        __syncthreads();
        #pragma unroll 1
        for (int k = 0; k < SC_CHUNK / 512; ++k) {
            const int e = cbase + k * 512 + t;
            if (e < N_EDGES) atomicAdd(&hist[dst[e] >> 8], 1);
        }
        __syncthreads();
        for (int i = t; i < NB; i += 512) {
            const int c = hist[i];
            gb[i] = c ? (i * CAP + atomicAdd(&bcnt[i], c)) : 0;
        }
        __syncthreads();
        #pragma unroll 1
        for (int k = 0; k < SC_CHUNK / 512; ++k) {
            const int e = cbase + k * 512 + t;
            if (e < N_EDGES) {
                const int d = dst[e];
                const int bkt = d >> 8;
                const int r = atomicAdd(&lcur[bkt], 1);
                sorted_c[gb[bkt] + r] = pack_entry(d, src[e], et[e]);
            }
        }
    } else if (b < NCH + CVT_BLOCKS) {  // ---- feat -> bf16 ----
        const int bb = b - NCH;
        const int total = N_NODES * 16;    // float4 count
        const float4* __restrict__ f4 = (const float4*)feat;
        uint2* __restrict__ o2 = (uint2*)fbf;
        for (int i = bb * 512 + t; i < total; i += CVT_BLOCKS * 512) {
            const float4 f = f4[i];
            uint2 o;
            o.x = bf16_rne(f.x) | (bf16_rne(f.y) << 16);
            o.y = bf16_rne(f.z) | (bf16_rne(f.w) << 16);
            o2[i] = o;
        }
    } else {  // ---- Wcat^T -> bf16 padded (64 x LROW) ----
        const int idx = (b - NCH - CVT_BLOCKS) * 512 + t;  // 25*512 = 12800
        const int n = idx / LROW, r = idx % LROW;
        float v = 0.0f;
        if (r < 128)      v = weight[r * 64 + n];          // V0;V1 rows contiguous
        else if (r < 192) v = loop_weight[(r - 128) * 64 + n];
        wtb[idx] = (unsigned short)bf16_rne(v);
    }
}

// ---------------------------------------------------------------- fine CSR
// base = b*CAP; end = base + bcnt[b]. 1024 threads; scan on t<256.
__global__ __launch_bounds__(1024) void k_fine(const unsigned* __restrict__ sorted_c,
                                               const int* __restrict__ bcnt,
                                               int* __restrict__ offs,
                                               int* __restrict__ ends,
                                               unsigned* __restrict__ sorted_f) {
    __shared__ int cnt[BN];
    __shared__ int part[BN];
    __shared__ int cur[BN];
    const int t = threadIdx.x;
    const int b = blockIdx.x;
    if (t < BN) cnt[t] = 0;
    __syncthreads();
    const int base = b * CAP;
    const int end  = base + bcnt[b];
    for (int k = base + t; k < end; k += 1024)
        atomicAdd(&cnt[sorted_c[k] & (BN - 1)], 1);
    __syncthreads();
    int v = 0;
    if (t < BN) {
        v = cnt[t];
        part[t] = v;
    }
    __syncthreads();
    for (int d = 1; d < BN; d <<= 1) {
        const int u = (t < BN && t >= d) ? part[t - d] : 0;
        __syncthreads();
        if (t < BN) part[t] += u;
        __syncthreads();
    }
    if (t < BN) {
        const int node = b * BN + t;
        const int off = base + part[t] - v;   // exclusive within bucket (padded)
        if (node < N_NODES) { offs[node] = off; ends[node] = off + v; }
        cur[t] = off;
    }
    __syncthreads();
    for (int k = base + t; k < end; k += 1024) {
        const unsigned en = sorted_c[k];
        const int pos = atomicAdd(&cur[en & (BN - 1)], 1);
        sorted_f[pos] = en;
    }
}

// ---------------------------------------------------------------- fused
// 512 threads = 8 waves; 6250 blocks, 16 nodes each.
// Phase 1: interleaved A/B pair, 3-stage pipeline:
//   stage n:  FMA batch n (feats issued at stage n-1)
//   stage n:  issue entries batch n+1 (no deps), then feats batch n+1
//   -> ~32 feat loads in flight per wave continuously.
// Phase 2: waves 0-3 = N-tile w; 6 mfma 16x16x32 with B-fragments in regs.
__global__ __launch_bounds__(512, 4) void k_gather_post(
    const int*      __restrict__ offs,
    const int*      __restrict__ ends,
    const unsigned* __restrict__ sorted_f,
    const float*    __restrict__ w_comp,      // (64, 2)
    const unsigned short* __restrict__ fbs,   // (N, 64) bf16
    const unsigned short* __restrict__ wtb,   // (64, LROW) bf16 = Wcat^T padded
    const float*    __restrict__ h_bias,      // (64,)
    float*          __restrict__ out)         // (N, 64)
{
    __shared__ unsigned short LinS[NPG * LROW]; // 6.4 KB
    __shared__ float2 wcl[64];

    const int tid  = threadIdx.x;
    const int lane = tid & 63;
    const int w    = tid >> 6;
    const int r16  = lane & 15;
    const int q    = lane >> 4;

    if (tid < 64) wcl[tid] = ((const float2*)w_comp)[tid];

    // Phase-2 B fragments: issued NOW, consumed after phase 1.
    bf16x8 bfrag[6];
    if (w < 4) {
        #pragma unroll
        for (int kt = 0; kt < 6; ++kt)
            bfrag[kt] = *(const bf16x8*)&wtb[(w * 16 + r16) * LROW + kt * 32 + q * 8];
    }
    __syncthreads();   // wcl visible

    const int grp = blockIdx.x;

    // ---- Phase 1: interleaved pair, feat loads pipelined 1 batch ahead ----
    {
        const int nA = __builtin_amdgcn_readfirstlane(grp * NPG + 2 * w);
        const int nB = nA + 1;
        const int sA = __builtin_amdgcn_readfirstlane(offs[nA]);
        const int eA = __builtin_amdgcn_readfirstlane(ends[nA]);
        const int sB = __builtin_amdgcn_readfirstlane(offs[nB]);
        const int eB = __builtin_amdgcn_readfirstlane(ends[nB]);
        const unsigned short fvA = fbs[(size_t)nA * 64 + lane];  // early issue
        const unsigned short fvB = fbs[(size_t)nB * 64 + lane];

        float aA0 = 0.f, bA0 = 0.f, aA1 = 0.f, bA1 = 0.f;
        float aB0 = 0.f, bB0 = 0.f, aB1 = 0.f, bB1 = 0.f;
        int kA = sA, kB = sB;

        if (kA + 7 < eA && kB + 7 < eB) {
            unsigned pA[8], pB[8];
            float fA[8], fB[8];
            #pragma unroll
            for (int i = 0; i < 8; ++i) pA[i] = sorted_f[kA + i];   // entries 0
            #pragma unroll
            for (int i = 0; i < 8; ++i) pB[i] = sorted_f[kB + i];
            #pragma unroll
            for (int i = 0; i < 8; ++i)                              // feats 0
                fA[i] = __uint_as_float(
                    (unsigned)fbs[(size_t)((pA[i] >> 8) & 0x1FFFF) * 64 + lane] << 16);
            #pragma unroll
            for (int i = 0; i < 8; ++i)
                fB[i] = __uint_as_float(
                    (unsigned)fbs[(size_t)((pB[i] >> 8) & 0x1FFFF) * 64 + lane] << 16);

            #pragma unroll 1
            while (kA + 15 < eA && kB + 15 < eB) {
                // stage: issue entries+feats for batch n+1 while feats n fly
                unsigned qA[8], qB[8];
                float gA[8], gB[8];
                #pragma unroll
                for (int i = 0; i < 8; ++i) qA[i] = sorted_f[kA + 8 + i];
                #pragma unroll
                for (int i = 0; i < 8; ++i) qB[i] = sorted_f[kB + 8 + i];
                #pragma unroll
                for (int i = 0; i < 8; ++i)
                    gA[i] = __uint_as_float(
                        (unsigned)fbs[(size_t)((qA[i] >> 8) & 0x1FFFF) * 64 + lane] << 16);
                #pragma unroll
                for (int i = 0; i < 8; ++i)
                    gB[i] = __uint_as_float(
                        (unsigned)fbs[(size_t)((qB[i] >> 8) & 0x1FFFF) * 64 + lane] << 16);
                // FMA batch n (waits only on fA/fB)
                #pragma unroll
                for (int i = 0; i < 8; ++i) {
                    const float2 c = wcl[pA[i] >> 25];
                    if (i & 1) { aA1 = fmaf(c.x, fA[i], aA1); bA1 = fmaf(c.y, fA[i], bA1); }
                    else       { aA0 = fmaf(c.x, fA[i], aA0); bA0 = fmaf(c.y, fA[i], bA0); }
                }
                #pragma unroll
                for (int i = 0; i < 8; ++i) {
                    const float2 c = wcl[pB[i] >> 25];
                    if (i & 1) { aB1 = fmaf(c.x, fB[i], aB1); bB1 = fmaf(c.y, fB[i], bB1); }
                    else       { aB0 = fmaf(c.x, fB[i], aB0); bB0 = fmaf(c.y, fB[i], bB0); }
                }
                kA += 8; kB += 8;
                #pragma unroll
                for (int i = 0; i < 8; ++i) {
                    pA[i] = qA[i]; pB[i] = qB[i];
                    fA[i] = gA[i]; fB[i] = gB[i];
                }
            }
            // last held batch
            #pragma unroll
            for (int i = 0; i < 8; ++i) {
                const float2 c = wcl[pA[i] >> 25];
                if (i & 1) { aA1 = fmaf(c.x, fA[i], aA1); bA1 = fmaf(c.y, fA[i], bA1); }
                else       { aA0 = fmaf(c.x, fA[i], aA0); bA0 = fmaf(c.y, fA[i], bA0); }
            }
            #pragma unroll
            for (int i = 0; i < 8; ++i) {
                const float2 c = wcl[pB[i] >> 25];
                if (i & 1) { aB1 = fmaf(c.x, fB[i], aB1); bB1 = fmaf(c.y, fB[i], bB1); }
                else       { aB0 = fmaf(c.x, fB[i], aB0); bB0 = fmaf(c.y, fB[i], bB0); }
            }
            kA += 8; kB += 8;
        }

        // drain node A (8/4/1 ladder)
        for (; kA + 7 < eA; kA += 8) {
            unsigned p[8]; float f[8];
            #pragma unroll
            for (int i = 0; i < 8; ++i) p[i] = sorted_f[kA + i];
            #pragma unroll
            for (int i = 0; i < 8; ++i)
                f[i] = __uint_as_float(
                    (unsigned)fbs[(size_t)((p[i] >> 8) & 0x1FFFF) * 64 + lane] << 16);
            #pragma unroll
            for (int i = 0; i < 8; ++i) {
                const float2 c = wcl[p[i] >> 25];
                if (i & 1) { aA1 = fmaf(c.x, f[i], aA1); bA1 = fmaf(c.y, f[i], bA1); }
                else       { aA0 = fmaf(c.x, f[i], aA0); bA0 = fmaf(c.y, f[i], bA0); }
            }
        }
        for (; kA + 3 < eA; kA += 4) {
            unsigned p[4]; float f[4];
            #pragma unroll
            for (int i = 0; i < 4; ++i) p[i] = sorted_f[kA + i];
            #pragma unroll
            for (int i = 0; i < 4; ++i)
                f[i] = __uint_as_float(
                    (unsigned)fbs[(size_t)((p[i] >> 8) & 0x1FFFF) * 64 + lane] << 16);
            #pragma unroll
            for (int i = 0; i < 4; ++i) {
                const float2 c = wcl[p[i] >> 25];
                if (i & 1) { aA1 = fmaf(c.x, f[i], aA1); bA1 = fmaf(c.y, f[i], bA1); }
                else       { aA0 = fmaf(c.x, f[i], aA0); bA0 = fmaf(c.y, f[i], bA0); }
            }
        }
        for (; kA < eA; ++kA) {
            const unsigned p0 = sorted_f[kA];
            const float f0 = __uint_as_float(
                (unsigned)fbs[(size_t)((p0 >> 8) & 0x1FFFF) * 64 + lane] << 16);
            const float2 c0 = wcl[p0 >> 25];
            aA0 = fmaf(c0.x, f0, aA0); bA0 = fmaf(c0.y, f0, bA0);
        }

        // drain node B
        for (; kB + 7 < eB; kB += 8) {
            unsigned p[8]; float f[8];
            #pragma unroll
            for (int i = 0; i < 8; ++i) p[i] = sorted_f[kB + i];
            #pragma unroll
            for (int i = 0; i < 8; ++i)
                f[i] = __uint_as_float(
                    (unsigned)fbs[(size_t)((p[i] >> 8) & 0x1FFFF) * 64 + lane] << 16);
            #pragma unroll
            for (int i = 0; i < 8; ++i) {
                const float2 c = wcl[p[i] >> 25];
                if (i & 1) { aB1 = fmaf(c.x, f[i], aB1); bB1 = fmaf(c.y, f[i], bB1); }
                else       { aB0 = fmaf(c.x, f[i], aB0); bB0 = fmaf(c.y, f[i], bB0); }
            }
        }
        for (; kB + 3 < eB; kB += 4) {
            unsigned p[4]; float f[4];
            #pragma unroll
            for (int i = 0; i < 4; ++i) p[i] = sorted_f[kB + i];
            #pragma unroll
            for (int i = 0; i < 4; ++i)
                f[i] = __uint_as_float(
                    (unsigned)fbs[(size_t)((p[i] >> 8) & 0x1FFFF) * 64 + lane] << 16);
            #pragma unroll
            for (int i = 0; i < 4; ++i) {
                const float2 c = wcl[p[i] >> 25];
                if (i & 1) { aB1 = fmaf(c.x, f[i], aB1); bB1 = fmaf(c.y, f[i], bB1); }
                else       { aB0 = fmaf(c.x, f[i], aB0); bB0 = fmaf(c.y, f[i], bB0); }
            }
        }
        for (; kB < eB; ++kB) {
            const unsigned p0 = sorted_f[kB];
            const float f0 = __uint_as_float(
                (unsigned)fbs[(size_t)((p0 >> 8) & 0x1FFFF) * 64 + lane] << 16);
            const float2 c0 = wcl[p0 >> 25];
            aB0 = fmaf(c0.x, f0, aB0); bB0 = fmaf(c0.y, f0, bB0);
        }

        const int slotA = 2 * w, slotB = 2 * w + 1;
        LinS[slotA * LROW + lane]       = (unsigned short)bf16_rne(aA0 + aA1);
        LinS[slotA * LROW + 64 + lane]  = (unsigned short)bf16_rne(bA0 + bA1);
        LinS[slotA * LROW + 128 + lane] = fvA;
        LinS[slotB * LROW + lane]       = (unsigned short)bf16_rne(aB0 + aB1);
        LinS[slotB * LROW + 64 + lane]  = (unsigned short)bf16_rne(bB0 + bB1);
        LinS[slotB * LROW + 128 + lane] = fvB;
    }
    __syncthreads();

    // ---- Phase 2: 16x64x192 via MFMA; wave w (<4) = N-tile w ----
    if (w < 4) {
        const float bv = h_bias[w * 16 + r16];
        f32x4 acc = {bv, bv, bv, bv};
        #pragma unroll
        for (int kt = 0; kt < 6; ++kt) {
            const bf16x8 a = *(const bf16x8*)&LinS[r16 * LROW + kt * 32 + q * 8];
            acc = __builtin_amdgcn_mfma_f32_16x16x32_bf16(a, bfrag[kt], acc, 0, 0, 0);
        }
        #pragma unroll
        for (int r = 0; r < 4; ++r)
            out[(size_t)(grp * NPG + q * 4 + r) * 64 + w * 16 + r16] = acc[r];
    }
}

// ---------------------------------------------------------------- launch
extern "C" void kernel_launch(void* const* d_in, const int* in_sizes, int n_in,
                              void* d_out, int out_size, void* d_ws, size_t ws_size,
                              hipStream_t stream) {
    const float* feat        = (const float*)d_in[0];
    const float* weight      = (const float*)d_in[1];
    const float* w_comp      = (const float*)d_in[2];
    const float* loop_weight = (const float*)d_in[3];
    const float* h_bias      = (const float*)d_in[4];
    const int*   src         = (const int*)d_in[5];
    const int*   dst         = (const int*)d_in[6];
    const int*   etypes      = (const int*)d_in[7];
    float* out = (float*)d_out;

    // ws layout (4B units), ~28 MB total, no aliasing:
    unsigned* sorted_c = (unsigned*)d_ws;                     // NB*CAP u32 (padded)
    unsigned* sorted_f = sorted_c + (size_t)NB * CAP;         // NB*CAP u32 (padded)
    unsigned* fbf      = sorted_f + (size_t)NB * CAP;         // 3.2M u32 (bf16 feat)
    unsigned* wtbu     = fbf + N_NODES * 32;                  // 6400 u32 (bf16 Wcat^T)
    int*      offs     = (int*)(wtbu + 64 * LROW / 2);        // N
    int*      ends     = offs + N_NODES;                      // N
    int*      bcnt     = ends + N_NODES;                      // NB

    hipMemsetAsync(bcnt, 0, NB * sizeof(int), stream);
    k_scatter_prep<<<NCH + CVT_BLOCKS + W_BLOCKS, 512, 0, stream>>>(
        src, dst, etypes, bcnt, sorted_c, feat, fbf, weight, loop_weight,
        (unsigned short*)wtbu);
    k_fine<<<NB, 1024, 0, stream>>>(sorted_c, bcnt, offs, ends, sorted_f);
    k_gather_post<<<N_GRP, 512, 0, stream>>>(offs, ends, sorted_f, w_comp,
                                             (const unsigned short*)fbf,
                                             (const unsigned short*)wtbu,
                                             h_bias, out);
}

// Round 22
// 101.329 us; speedup vs baseline: 1.1575x; 1.1575x over previous
//
#include <hip/hip_runtime.h>

// RelGraphConv basis-decomposition forward, MI355X.
//
// Input-space reformulation:
//   g[d, b, :] = sum_{e: dst_e = d} w_comp[et_e, b] * feat[src_e, :]   (b = 0,1)
//   out[d]     = [g0 | g1 | feat](192) @ Wcat(192x64) + bias,
//                Wcat = [V0; V1; W_loop]
//
// Pipeline (3 dispatches + memset):
//   memset(bcnt)  : per-bucket counts start at 0
//   k_scatter_prep: 512 thr; blocks 0..195 = coarse 391-bucket multisplit
//                   (SC_CHUNK=8192); REGISTER-CACHED entries: hist pass
//                   packs+stores the 16 edges/thread so the scatter pass
//                   re-reads nothing. Then feat->bf16; Wcat^T->bf16.
//   k_fine        : per-bucket exact per-node CSR (LDS hist+scan, 1024 thr)
//   k_gather_post : r19-verbatim (best measured: 57us). 16 nodes/block,
//                   interleaved A/B pair + next-batch entry prefetch;
//                   phase 2 = 16x64x192 MFMA tile, B-fragments in regs.
//
// History: r20 (NPG=32) and r21 (3-stage feat pipeline) both regressed the
// gather via VGPR/occupancy; 57us is this structure's operating point.

constexpr int N_NODES  = 100000;
constexpr int N_EDGES  = 1600000;
constexpr int IN_FEAT  = 64;
constexpr int OUT_FEAT = 64;

constexpr int BN  = 256;                               // nodes per bucket
constexpr int NB  = (N_NODES + BN - 1) / BN;           // 391 buckets
constexpr int CAP = 4608;                              // bucket capacity (+8 sigma)
constexpr int SC_CHUNK = 8192;                         // edges per scatter block
constexpr int NCH = (N_EDGES + SC_CHUNK - 1) / SC_CHUNK;  // 196 scatter blocks
constexpr int EPT = SC_CHUNK / 512;                    // 16 edges per thread
constexpr int CVT_BLOCKS = 512;                        // feat cvt blocks (512 thr)
constexpr int W_BLOCKS = 25;                           // 64*LROW/512 wtb blocks

constexpr int NPG = 16;                                // nodes per gather block
constexpr int N_GRP = N_NODES / NPG;                   // 6250 (exact)
constexpr int LROW = 200;                              // padded row (bf16)

typedef __attribute__((ext_vector_type(8))) short bf16x8;
typedef __attribute__((ext_vector_type(4))) float f32x4;

// entry pack: dst_low(8) | src(17) | etype(6)
__device__ __forceinline__ unsigned pack_entry(int d, int s, int r) {
    return (unsigned)(d & (BN - 1)) | ((unsigned)s << 8) | ((unsigned)r << 25);
}

__device__ __forceinline__ unsigned bf16_rne(float f) {
    unsigned b = __float_as_uint(f);
    b += 0x7fffu + ((b >> 16) & 1u);
    return b >> 16;
}

// ------------------------------------------------- fused scatter + convert
__global__ __launch_bounds__(512) void k_scatter_prep(
    const int* __restrict__ src, const int* __restrict__ dst,
    const int* __restrict__ et,  int* __restrict__ bcnt,
    unsigned* __restrict__ sorted_c,
    const float* __restrict__ feat, unsigned* __restrict__ fbf,
    const float* __restrict__ weight, const float* __restrict__ loop_weight,
    unsigned short* __restrict__ wtb)
{
    __shared__ int hist[NB], gb[NB], lcur[NB];
    const int b = blockIdx.x, t = threadIdx.x;

    if (b < NCH) {  // ---- multisplit scatter chunk (register-cached) ----
        const int cbase = b * SC_CHUNK;
        for (int i = t; i < NB; i += 512) { hist[i] = 0; lcur[i] = 0; }
        __syncthreads();
        unsigned ent[EPT];
        unsigned short bkt[EPT];
        #pragma unroll 1
        for (int k = 0; k < EPT; ++k) {
            const int e = cbase + k * 512 + t;
            if (e < N_EDGES) {
                const int d = dst[e];
                ent[k] = pack_entry(d, src[e], et[e]);
                bkt[k] = (unsigned short)(d >> 8);
                atomicAdd(&hist[d >> 8], 1);
            } else {
                bkt[k] = 0xFFFF;
            }
        }
        __syncthreads();
        for (int i = t; i < NB; i += 512) {
            const int c = hist[i];
            gb[i] = c ? (i * CAP + atomicAdd(&bcnt[i], c)) : 0;
        }
        __syncthreads();
        #pragma unroll 1
        for (int k = 0; k < EPT; ++k) {
            if (bkt[k] != 0xFFFF) {
                const int bi = bkt[k];
                const int r = atomicAdd(&lcur[bi], 1);
                sorted_c[gb[bi] + r] = ent[k];
            }
        }
    } else if (b < NCH + CVT_BLOCKS) {  // ---- feat -> bf16 ----
        const int bb = b - NCH;
        const int total = N_NODES * 16;    // float4 count
        const float4* __restrict__ f4 = (const float4*)feat;
        uint2* __restrict__ o2 = (uint2*)fbf;
        for (int i = bb * 512 + t; i < total; i += CVT_BLOCKS * 512) {
            const float4 f = f4[i];
            uint2 o;
            o.x = bf16_rne(f.x) | (bf16_rne(f.y) << 16);
            o.y = bf16_rne(f.z) | (bf16_rne(f.w) << 16);
            o2[i] = o;
        }
    } else {  // ---- Wcat^T -> bf16 padded (64 x LROW) ----
        const int idx = (b - NCH - CVT_BLOCKS) * 512 + t;  // 25*512 = 12800
        const int n = idx / LROW, r = idx % LROW;
        float v = 0.0f;
        if (r < 128)      v = weight[r * 64 + n];          // V0;V1 rows contiguous
        else if (r < 192) v = loop_weight[(r - 128) * 64 + n];
        wtb[idx] = (unsigned short)bf16_rne(v);
    }
}

// ---------------------------------------------------------------- fine CSR
// base = b*CAP; end = base + bcnt[b]. 1024 threads; scan on t<256.
__global__ __launch_bounds__(1024) void k_fine(const unsigned* __restrict__ sorted_c,
                                               const int* __restrict__ bcnt,
                                               int* __restrict__ offs,
                                               int* __restrict__ ends,
                                               unsigned* __restrict__ sorted_f) {
    __shared__ int cnt[BN];
    __shared__ int part[BN];
    __shared__ int cur[BN];
    const int t = threadIdx.x;
    const int b = blockIdx.x;
    if (t < BN) cnt[t] = 0;
    __syncthreads();
    const int base = b * CAP;
    const int end  = base + bcnt[b];
    for (int k = base + t; k < end; k += 1024)
        atomicAdd(&cnt[sorted_c[k] & (BN - 1)], 1);
    __syncthreads();
    int v = 0;
    if (t < BN) {
        v = cnt[t];
        part[t] = v;
    }
    __syncthreads();
    for (int d = 1; d < BN; d <<= 1) {
        const int u = (t < BN && t >= d) ? part[t - d] : 0;
        __syncthreads();
        if (t < BN) part[t] += u;
        __syncthreads();
    }
    if (t < BN) {
        const int node = b * BN + t;
        const int off = base + part[t] - v;   // exclusive within bucket (padded)
        if (node < N_NODES) { offs[node] = off; ends[node] = off + v; }
        cur[t] = off;
    }
    __syncthreads();
    for (int k = base + t; k < end; k += 1024) {
        const unsigned en = sorted_c[k];
        const int pos = atomicAdd(&cur[en & (BN - 1)], 1);
        sorted_f[pos] = en;
    }
}

// ---------------------------------------------------------------- fused
// 512 threads = 8 waves; 6250 blocks, 16 nodes each. (r19-verbatim)
__global__ __launch_bounds__(512, 4) void k_gather_post(
    const int*      __restrict__ offs,
    const int*      __restrict__ ends,
    const unsigned* __restrict__ sorted_f,
    const float*    __restrict__ w_comp,      // (64, 2)
    const unsigned short* __restrict__ fbs,   // (N, 64) bf16
    const unsigned short* __restrict__ wtb,   // (64, LROW) bf16 = Wcat^T padded
    const float*    __restrict__ h_bias,      // (64,)
    float*          __restrict__ out)         // (N, 64)
{
    __shared__ unsigned short LinS[NPG * LROW]; // 6.4 KB
    __shared__ float2 wcl[64];

    const int tid  = threadIdx.x;
    const int lane = tid & 63;
    const int w    = tid >> 6;
    const int r16  = lane & 15;
    const int q    = lane >> 4;

    if (tid < 64) wcl[tid] = ((const float2*)w_comp)[tid];

    // Phase-2 B fragments: issued NOW, consumed after phase 1.
    bf16x8 bfrag[6];
    if (w < 4) {
        #pragma unroll
        for (int kt = 0; kt < 6; ++kt)
            bfrag[kt] = *(const bf16x8*)&wtb[(w * 16 + r16) * LROW + kt * 32 + q * 8];
    }
    __syncthreads();   // wcl visible

    const int grp = blockIdx.x;

    // ---- Phase 1: two nodes per wave, interleaved + entry prefetch ----
    {
        const int nA = __builtin_amdgcn_readfirstlane(grp * NPG + 2 * w);
        const int nB = nA + 1;
        const int sA = __builtin_amdgcn_readfirstlane(offs[nA]);
        const int eA = __builtin_amdgcn_readfirstlane(ends[nA]);
        const int sB = __builtin_amdgcn_readfirstlane(offs[nB]);
        const int eB = __builtin_amdgcn_readfirstlane(ends[nB]);
        const unsigned short fvA = fbs[(size_t)nA * 64 + lane];  // early issue
        const unsigned short fvB = fbs[(size_t)nB * 64 + lane];

        float aA0 = 0.f, bA0 = 0.f, aA1 = 0.f, bA1 = 0.f;
        float aB0 = 0.f, bB0 = 0.f, aB1 = 0.f, bB1 = 0.f;
        int kA = sA, kB = sB;

        if (kA + 7 < eA && kB + 7 < eB) {
            unsigned pA[8], pB[8];
            #pragma unroll
            for (int i = 0; i < 8; ++i) pA[i] = sorted_f[kA + i];   // s_load
            #pragma unroll
            for (int i = 0; i < 8; ++i) pB[i] = sorted_f[kB + i];
            #pragma unroll 1
            while (true) {
                float fA[8], fB[8];
                #pragma unroll
                for (int i = 0; i < 8; ++i)
                    fA[i] = __uint_as_float(
                        (unsigned)fbs[(size_t)((pA[i] >> 8) & 0x1FFFF) * 64 + lane] << 16);
                #pragma unroll
                for (int i = 0; i < 8; ++i)
                    fB[i] = __uint_as_float(
                        (unsigned)fbs[(size_t)((pB[i] >> 8) & 0x1FFFF) * 64 + lane] << 16);
                const bool more = (kA + 15 < eA) && (kB + 15 < eB);
                unsigned qA[8], qB[8];
                if (more) {   // prefetch next batch entries under VMEM latency
                    #pragma unroll
                    for (int i = 0; i < 8; ++i) qA[i] = sorted_f[kA + 8 + i];
                    #pragma unroll
                    for (int i = 0; i < 8; ++i) qB[i] = sorted_f[kB + 8 + i];
                }
                #pragma unroll
                for (int i = 0; i < 8; ++i) {
                    const float2 c = wcl[pA[i] >> 25];
                    if (i & 1) { aA1 = fmaf(c.x, fA[i], aA1); bA1 = fmaf(c.y, fA[i], bA1); }
                    else       { aA0 = fmaf(c.x, fA[i], aA0); bA0 = fmaf(c.y, fA[i], bA0); }
                }
                #pragma unroll
                for (int i = 0; i < 8; ++i) {
                    const float2 c = wcl[pB[i] >> 25];
                    if (i & 1) { aB1 = fmaf(c.x, fB[i], aB1); bB1 = fmaf(c.y, fB[i], bB1); }
                    else       { aB0 = fmaf(c.x, fB[i], aB0); bB0 = fmaf(c.y, fB[i], bB0); }
                }
                kA += 8; kB += 8;
                if (!more) break;
                #pragma unroll
                for (int i = 0; i < 8; ++i) { pA[i] = qA[i]; pB[i] = qB[i]; }
            }
        }

        // drain node A (8/4/1 ladder)
        for (; kA + 7 < eA; kA += 8) {
            unsigned p[8]; float f[8];
            #pragma unroll
            for (int i = 0; i < 8; ++i) p[i] = sorted_f[kA + i];
            #pragma unroll
            for (int i = 0; i < 8; ++i)
                f[i] = __uint_as_float(
                    (unsigned)fbs[(size_t)((p[i] >> 8) & 0x1FFFF) * 64 + lane] << 16);
            #pragma unroll
            for (int i = 0; i < 8; ++i) {
                const float2 c = wcl[p[i] >> 25];
                if (i & 1) { aA1 = fmaf(c.x, f[i], aA1); bA1 = fmaf(c.y, f[i], bA1); }
                else       { aA0 = fmaf(c.x, f[i], aA0); bA0 = fmaf(c.y, f[i], bA0); }
            }
        }
        for (; kA + 3 < eA; kA += 4) {
            unsigned p[4]; float f[4];
            #pragma unroll
            for (int i = 0; i < 4; ++i) p[i] = sorted_f[kA + i];
            #pragma unroll
            for (int i = 0; i < 4; ++i)
                f[i] = __uint_as_float(
                    (unsigned)fbs[(size_t)((p[i] >> 8) & 0x1FFFF) * 64 + lane] << 16);
            #pragma unroll
            for (int i = 0; i < 4; ++i) {
                const float2 c = wcl[p[i] >> 25];
                if (i & 1) { aA1 = fmaf(c.x, f[i], aA1); bA1 = fmaf(c.y, f[i], bA1); }
                else       { aA0 = fmaf(c.x, f[i], aA0); bA0 = fmaf(c.y, f[i], bA0); }
            }
        }
        for (; kA < eA; ++kA) {
            const unsigned p0 = sorted_f[kA];
            const float f0 = __uint_as_float(
                (unsigned)fbs[(size_t)((p0 >> 8) & 0x1FFFF) * 64 + lane] << 16);
            const float2 c0 = wcl[p0 >> 25];
            aA0 = fmaf(c0.x, f0, aA0); bA0 = fmaf(c0.y, f0, bA0);
        }

        // drain node B
        for (; kB + 7 < eB; kB += 8) {
            unsigned p[8]; float f[8];
            #pragma unroll
            for (int i = 0; i < 8; ++i) p[i] = sorted_f[kB + i];
            #pragma unroll
            for (int i = 0; i < 8; ++i)
                f[i] = __uint_as_float(
                    (unsigned)fbs[(size_t)((p[i] >> 8) & 0x1FFFF) * 64 + lane] << 16);
            #pragma unroll
            for (int i = 0; i < 8; ++i) {
                const float2 c = wcl[p[i] >> 25];
                if (i & 1) { aB1 = fmaf(c.x, f[i], aB1); bB1 = fmaf(c.y, f[i], bB1); }
                else       { aB0 = fmaf(c.x, f[i], aB0); bB0 = fmaf(c.y, f[i], bB0); }
            }
        }
        for (; kB + 3 < eB; kB += 4) {
            unsigned p[4]; float f[4];
            #pragma unroll
            for (int i = 0; i < 4; ++i) p[i] = sorted_f[kB + i];
            #pragma unroll
            for (int i = 0; i < 4; ++i)
                f[i] = __uint_as_float(
                    (unsigned)fbs[(size_t)((p[i] >> 8) & 0x1FFFF) * 64 + lane] << 16);
            #pragma unroll
            for (int i = 0; i < 4; ++i) {
                const float2 c = wcl[p[i] >> 25];
                if (i & 1) { aB1 = fmaf(c.x, f[i], aB1); bB1 = fmaf(c.y, f[i], bB1); }
                else       { aB0 = fmaf(c.x, f[i], aB0); bB0 = fmaf(c.y, f[i], bB0); }
            }
        }
        for (; kB < eB; ++kB) {
            const unsigned p0 = sorted_f[kB];
            const float f0 = __uint_as_float(
                (unsigned)fbs[(size_t)((p0 >> 8) & 0x1FFFF) * 64 + lane] << 16);
            const float2 c0 = wcl[p0 >> 25];
            aB0 = fmaf(c0.x, f0, aB0); bB0 = fmaf(c0.y, f0, bB0);
        }

        const int slotA = 2 * w, slotB = 2 * w + 1;
        LinS[slotA * LROW + lane]       = (unsigned short)bf16_rne(aA0 + aA1);
        LinS[slotA * LROW + 64 + lane]  = (unsigned short)bf16_rne(bA0 + bA1);
        LinS[slotA * LROW + 128 + lane] = fvA;
        LinS[slotB * LROW + lane]       = (unsigned short)bf16_rne(aB0 + aB1);
        LinS[slotB * LROW + 64 + lane]  = (unsigned short)bf16_rne(bB0 + bB1);
        LinS[slotB * LROW + 128 + lane] = fvB;
    }
    __syncthreads();

    // ---- Phase 2: 16x64x192 via MFMA; wave w (<4) = N-tile w ----
    if (w < 4) {
        const float bv = h_bias[w * 16 + r16];
        f32x4 acc = {bv, bv, bv, bv};
        #pragma unroll
        for (int kt = 0; kt < 6; ++kt) {
            const bf16x8 a = *(const bf16x8*)&LinS[r16 * LROW + kt * 32 + q * 8];
            acc = __builtin_amdgcn_mfma_f32_16x16x32_bf16(a, bfrag[kt], acc, 0, 0, 0);
        }
        #pragma unroll
        for (int r = 0; r < 4; ++r)
            out[(size_t)(grp * NPG + q * 4 + r) * 64 + w * 16 + r16] = acc[r];
    }
}

// ---------------------------------------------------------------- launch
extern "C" void kernel_launch(void* const* d_in, const int* in_sizes, int n_in,
                              void* d_out, int out_size, void* d_ws, size_t ws_size,
                              hipStream_t stream) {
    const float* feat        = (const float*)d_in[0];
    const float* weight      = (const float*)d_in[1];
    const float* w_comp      = (const float*)d_in[2];
    const float* loop_weight = (const float*)d_in[3];
    const float* h_bias      = (const float*)d_in[4];
    const int*   src         = (const int*)d_in[5];
    const int*   dst         = (const int*)d_in[6];
    const int*   etypes      = (const int*)d_in[7];
    float* out = (float*)d_out;

    // ws layout (4B units), ~28 MB total, no aliasing:
    unsigned* sorted_c = (unsigned*)d_ws;                     // NB*CAP u32 (padded)
    unsigned* sorted_f = sorted_c + (size_t)NB * CAP;         // NB*CAP u32 (padded)
    unsigned* fbf      = sorted_f + (size_t)NB * CAP;         // 3.2M u32 (bf16 feat)
    unsigned* wtbu     = fbf + N_NODES * 32;                  // 6400 u32 (bf16 Wcat^T)
    int*      offs     = (int*)(wtbu + 64 * LROW / 2);        // N
    int*      ends     = offs + N_NODES;                      // N
    int*      bcnt     = ends + N_NODES;                      // NB

    hipMemsetAsync(bcnt, 0, NB * sizeof(int), stream);
    k_scatter_prep<<<NCH + CVT_BLOCKS + W_BLOCKS, 512, 0, stream>>>(
        src, dst, etypes, bcnt, sorted_c, feat, fbf, weight, loop_weight,
        (unsigned short*)wtbu);
    k_fine<<<NB, 1024, 0, stream>>>(sorted_c, bcnt, offs, ends, sorted_f);
    k_gather_post<<<N_GRP, 512, 0, stream>>>(offs, ends, sorted_f, w_comp,
                                             (const unsigned short*)fbf,
                                             (const unsigned short*)wtbu,
                                             h_bias, out);
}